// Round 19
// baseline (38.420 us; speedup 1.0000x reference)
//
#include <hip/hip_runtime.h>

// Modulated deformable depthwise conv, B=8 C=128 H=W=64 K=3 PAD=1 STRIDE=1.
// Round 18: block-turnover pipelining. Round 13's channel loop restages the
// window per group anyway (no staging dedup) -- so split each group into its
// own small block: CH=4, NIT=1, stage -> ONE barrier -> compute -> exit.
// Removes cross-iteration stg liveness (VGPR ~85, stg dies at the barrier),
// halves LDS to one 18.9KB buffer, grid 4096 = 16 blocks/CU rolling at
// different phases (loads of some blocks hide under compute of others).
// Metadata is recomputed per 4 channels (+40% VALU, L2-absorbed re-reads);
// cg-fastest block order: 32 consecutive blocks share identical metadata.
// Total global loads / LDS writes / LDS reads are IDENTICAL to round 13.

#define BB 8
#define CC 128
#define HH 64
#define WW 64
#define HWs (HH*WW)
#define KKT 9
#define CH 4               // channels per block (one float4 cell group)
#define NCG (CC/CH)        // 32
#define ROWS 4
#define NHS (HH/ROWS)      // 16
#define WLO 5
#define WR  (ROWS+12)      // 16 staged rows
#define CLO 5
#define WC  74             // cols -5 .. 68
#define CELLS (WR*WC)      // 1184 float4 cells = 18.9 KB (single buffer)
#define NTHR 256
#define NK  ((CELLS + NTHR - 1)/NTHR)   // 5

__global__ __launch_bounds__(NTHR, 2)
void mdcn_kernel(const float* __restrict__ x,
                 const float* __restrict__ offset,
                 const float* __restrict__ mask,
                 const float* __restrict__ dynw,
                 float* __restrict__ out)
{
    __shared__ float4 lds[CELLS];

    // cg fastest: 32 consecutive blocks share (b,hs) -> identical metadata
    const int blk = blockIdx.x;
    const int cg = blk & (NCG - 1);
    const int r  = blk >> 5;
    const int hs = r & (NHS - 1);
    const int b  = r >> 4;
    const int tid = threadIdx.x;
    const int w = tid & 63;
    const int h0 = hs * ROWS;
    const int h = h0 + (tid >> 6);

    const float* xg = x + (size_t)(b * CC + cg * CH) * HWs;

    // ---- issue staging loads (latency hidden under metadata compute) ----
    float4 stg[NK];
    #pragma unroll
    for (int k = 0; k < NK; ++k) {
        const int idx = tid + k * NTHR;
        float4 v = make_float4(0.f, 0.f, 0.f, 0.f);
        if (idx < CELLS) {
            const int row = idx / WC;
            const int col = idx - row * WC - CLO;
            const int ar  = h0 - WLO + row;
            if ((unsigned)ar < (unsigned)HH && (unsigned)col < (unsigned)WW) {
                const float* pp = xg + ar * WW + col;
                v.x = pp[0 * HWs]; v.y = pp[1 * HWs];
                v.z = pp[2 * HWs]; v.w = pp[3 * HWs];
            }
        }
        stg[k] = v;
    }

    // ---- per-tap metadata: m, dy, dx + window offset (overlaps loads) ----
    float mv[KKT], dyv[KKT], dxv[KKT];
    int   woff[KKT];
    int   badmask = 0;
    const float* offp = offset + (size_t)b * (2 * KKT) * HWs + h * WW + w;
    const float* mskp = mask   + (size_t)b * KKT * HWs       + h * WW + w;
    #pragma unroll
    for (int t = 0; t < KKT; ++t) {
        const float oy = offp[(2 * t)     * HWs];
        const float ox = offp[(2 * t + 1) * HWs];
        const float m  = mskp[t * HWs];
        const float py = (float)(h - 1 + t / 3) + oy;
        const float px = (float)(w - 1 + t % 3) + ox;
        const float fy = floorf(py), fx = floorf(px);
        const int y0 = (int)fy, x0 = (int)fx;
        dyv[t] = py - fy;
        dxv[t] = px - fx;
        const bool inwin = (y0 >= h0 - WLO) && (y0 <= h0 - WLO + WR - 2) &&
                           (x0 >= -CLO)     && (x0 <= -CLO + WC - 2);
        if (!inwin) {
            badmask |= (1 << t);
            woff[t] = 0;
            mv[t] = 0.f;               // zeroes the LDS contribution
        } else {
            woff[t] = (y0 - (h0 - WLO)) * WC + (x0 + CLO);
            mv[t] = m;                 // pads hold zeros -> no corner masks
        }
    }
    const int anybad = __any(badmask != 0);

    const float* wt   = dynw + (size_t)(b * CC + cg * CH) * KKT;
    float*       outp = out  + (size_t)(b * CC + cg * CH) * HWs + h * WW + w;

    float s0 = 0.f, s1 = 0.f, s2 = 0.f, s3 = 0.f;

    // rare corrective path (exact, from global; also overlaps load latency)
    if (anybad) {
        #pragma unroll
        for (int t = 0; t < KKT; ++t) {
            if (badmask & (1 << t)) {
                const float oy = offp[(2 * t)     * HWs];
                const float ox = offp[(2 * t + 1) * HWs];
                const float m  = mskp[t * HWs];
                const float py = (float)(h - 1 + t / 3) + oy;
                const float px = (float)(w - 1 + t % 3) + ox;
                const float fy = floorf(py), fx = floorf(px);
                const float dy = py - fy, dx = px - fx;
                const int y0 = (int)fy, x0 = (int)fx;
                const int y1 = y0 + 1,  x1 = x0 + 1;
                const int cy0 = min(max(y0, 0), HH - 1);
                const int cy1 = min(max(y1, 0), HH - 1);
                const int cx0 = min(max(x0, 0), WW - 1);
                const int cx1 = min(max(x1, 0), WW - 1);
                const float m00 = ((unsigned)y0 < HH && (unsigned)x0 < WW) ? 1.f : 0.f;
                const float m01 = ((unsigned)y0 < HH && (unsigned)x1 < WW) ? 1.f : 0.f;
                const float m10 = ((unsigned)y1 < HH && (unsigned)x0 < WW) ? 1.f : 0.f;
                const float m11 = ((unsigned)y1 < HH && (unsigned)x1 < WW) ? 1.f : 0.f;
                const float omdy = 1.f - dy, omdx = 1.f - dx;
                #pragma unroll
                for (int c = 0; c < CH; ++c) {
                    const float* pl = xg + (size_t)c * HWs;
                    const float v = pl[cy0 * WW + cx0] * m00 * (omdy * omdx)
                                  + pl[cy0 * WW + cx1] * m01 * (omdy * dx)
                                  + pl[cy1 * WW + cx0] * m10 * (dy * omdx)
                                  + pl[cy1 * WW + cx1] * m11 * (dy * dx);
                    const float add = v * m * wt[c * KKT + t];
                    if      (c == 0) s0 += add;
                    else if (c == 1) s1 += add;
                    else if (c == 2) s2 += add;
                    else             s3 += add;
                }
            }
        }
    }

    // ---- write window to LDS (vmcnt drains here), one barrier ----
    #pragma unroll
    for (int k = 0; k < NK; ++k) {
        const int idx = tid + k * NTHR;
        if (idx < CELLS) lds[idx] = stg[k];
    }
    __syncthreads();

    // ---- tap loop: 36 ds_read_b128, no further syncs ----
    #pragma unroll
    for (int t = 0; t < KKT; ++t) {
        const float4 c00 = lds[woff[t]];
        const float4 c01 = lds[woff[t] + 1];
        const float4 c10 = lds[woff[t] + WC];
        const float4 c11 = lds[woff[t] + WC + 1];
        const float dy = dyv[t], dx = dxv[t], m = mv[t];
        const float omdy = 1.f - dy, omdx = 1.f - dx;
        const float w00 = omdy * omdx * m, w01 = omdy * dx * m;
        const float w10 = dy * omdx * m,   w11 = dy * dx * m;
        const float v0 = c00.x * w00 + c01.x * w01 + c10.x * w10 + c11.x * w11;
        const float v1 = c00.y * w00 + c01.y * w01 + c10.y * w10 + c11.y * w11;
        const float v2 = c00.z * w00 + c01.z * w01 + c10.z * w10 + c11.z * w11;
        const float v3 = c00.w * w00 + c01.w * w01 + c10.w * w10 + c11.w * w11;
        s0 += v0 * wt[0 * KKT + t];
        s1 += v1 * wt[1 * KKT + t];
        s2 += v2 * wt[2 * KKT + t];
        s3 += v3 * wt[3 * KKT + t];
    }

    outp[0 * HWs] = s0;
    outp[1 * HWs] = s1;
    outp[2 * HWs] = s2;
    outp[3 * HWs] = s3;
}

extern "C" void kernel_launch(void* const* d_in, const int* in_sizes, int n_in,
                              void* d_out, int out_size, void* d_ws, size_t ws_size,
                              hipStream_t stream) {
    const float* x      = (const float*)d_in[0];
    const float* offset = (const float*)d_in[1];
    const float* mask   = (const float*)d_in[2];
    const float* dynw   = (const float*)d_in[3];
    float* out = (float*)d_out;

    dim3 grid(BB * NCG * NHS);   // 8 * 32 * 16 = 4096 blocks
    dim3 block(NTHR);
    mdcn_kernel<<<grid, block, 0, stream>>>(x, offset, mask, dynw, out);
}